// Round 1
// baseline (499.124 us; speedup 1.0000x reference)
//
#include <hip/hip_runtime.h>

// RNN-T joint: log_softmax(fc2(tanh(fc1(cat(enc,dec))))), fused.
// B=4, M=256, N=128, D=512, C=1024, JOINT=1024.
// ws layout: he f32 [1024][512] | hd f32 [512][512] | w2b bf16 [1024][512]  (4 MB)

typedef __attribute__((ext_vector_type(8))) __bf16 bf16x8;
typedef __attribute__((ext_vector_type(4))) float f32x4;

__device__ __forceinline__ float tanh_fast(float x) {
    // tanh(x) = 1 - 2/(1+e^{2x}); stable at both extremes (exp->0 or inf)
    float e = __expf(2.0f * x);
    return 1.0f - 2.0f / (e + 1.0f);
}

// Swizzled LDS byte offset for a [64 rows][512 k] bf16 tile (row stride 1024 B).
// XOR of bits 4-6 with row&7 spreads the 16B chunks of different rows across
// bank groups (stride-1024 would otherwise be a 16-way conflict on ds_read_b128).
__device__ __forceinline__ int swz(int row, int kbyte) {
    return row * 1024 + (kbyte ^ ((row & 7) << 4));
}

__device__ __forceinline__ bf16x8 cvt8(float4 a, float4 b) {
    bf16x8 r;
    r[0] = (__bf16)a.x; r[1] = (__bf16)a.y; r[2] = (__bf16)a.z; r[3] = (__bf16)a.w;
    r[4] = (__bf16)b.x; r[5] = (__bf16)b.y; r[6] = (__bf16)b.z; r[7] = (__bf16)b.w;
    return r;
}

// ---------------------------------------------------------------------------
// Prep: blocks 0..15 -> he (enc @ w1[:, :512]^T), 16..23 -> hd (dec @ w1[:, 512:]^T),
//       blocks 24..39 -> w2 f32 -> bf16 conversion.
// he[r][e] = sum_d enc[r][d] * w1[e][d]   (w1 row stride = 1024 floats)
// ---------------------------------------------------------------------------
__global__ __launch_bounds__(512) void k_prep(
    const float* __restrict__ enc, const float* __restrict__ dec,
    const float* __restrict__ w1, const float* __restrict__ w2,
    float* __restrict__ he, float* __restrict__ hd,
    unsigned short* __restrict__ w2b)
{
    const int bid = blockIdx.x, tid = threadIdx.x;

    if (bid >= 24) {  // w2 conversion: 1024*512 floats = 131072 float4s
        int t = (bid - 24) * 512 + tid;
        const float4* src = (const float4*)w2;
        ushort4* dst = (ushort4*)w2b;
        for (int i = t; i < 131072; i += 8192) {
            float4 v = src[i];
            ushort4 o;
            o.x = __builtin_bit_cast(unsigned short, (__bf16)v.x);
            o.y = __builtin_bit_cast(unsigned short, (__bf16)v.y);
            o.z = __builtin_bit_cast(unsigned short, (__bf16)v.z);
            o.w = __builtin_bit_cast(unsigned short, (__bf16)v.w);
            dst[i] = o;
        }
        return;
    }

    __shared__ uint4 ldsq[4096];           // 64 KB: A tile, 64 rows x 512 k bf16
    char* lds = (char*)ldsq;

    const bool ish = bid < 16;
    const int r0 = (ish ? bid : bid - 16) * 64;
    const float* src = (ish ? enc : dec) + r0 * 512;
    const float* wsrc = w1 + (ish ? 0 : 512);
    float* dst = (ish ? he : hd) + r0 * 512;

    // stage A tile (f32 -> bf16)
    const int row = tid >> 3, a = tid & 7;
    #pragma unroll
    for (int i = 0; i < 8; i++) {
        int k0 = (a + 8 * i) * 8;
        const float4* p = (const float4*)(src + row * 512 + k0);
        *(bf16x8*)(lds + swz(row, k0 * 2)) = cvt8(p[0], p[1]);
    }
    __syncthreads();

    const int lane = tid & 63, wid = tid >> 6, lr = lane & 15, lg = lane >> 4;
    f32x4 acc[4][4];
    #pragma unroll
    for (int rt = 0; rt < 4; rt++)
        #pragma unroll
        for (int ct = 0; ct < 4; ct++)
            acc[rt][ct] = f32x4{0.f, 0.f, 0.f, 0.f};

    #pragma unroll 1
    for (int ks = 0; ks < 512; ks += 32) {
        bf16x8 af[4];
        #pragma unroll
        for (int rt = 0; rt < 4; rt++)
            af[rt] = *(const bf16x8*)(lds + swz(rt * 16 + lr, ks * 2 + lg * 16));
        #pragma unroll
        for (int ct = 0; ct < 4; ct++) {
            int col = wid * 64 + ct * 16 + lr;
            const float4* wp = (const float4*)(wsrc + col * 1024 + ks + lg * 8);
            bf16x8 bfr = cvt8(wp[0], wp[1]);
            #pragma unroll
            for (int rt = 0; rt < 4; rt++)
                acc[rt][ct] = __builtin_amdgcn_mfma_f32_16x16x32_bf16(af[rt], bfr, acc[rt][ct], 0, 0, 0);
        }
    }

    #pragma unroll
    for (int rt = 0; rt < 4; rt++)
        #pragma unroll
        for (int ct = 0; ct < 4; ct++)
            #pragma unroll
            for (int reg = 0; reg < 4; reg++)
                dst[(rt * 16 + lg * 4 + reg) * 512 + wid * 64 + ct * 16 + lr] = acc[rt][ct][reg];
}

// ---------------------------------------------------------------------------
// Main fused kernel: block = 64 output rows (one (b,m), 64 consecutive n) x 1024 cols.
// hid = tanh(he[m]+hd[n]+b1) staged bf16 in LDS; GEMM vs w2b; +b2; log_softmax; store.
// 8 waves, each owns a 64x128 column slice -> acc[4 row-tiles][8 col-tiles] f32x4.
// ---------------------------------------------------------------------------
__global__ __launch_bounds__(512) void k_main(
    const float* __restrict__ he, const float* __restrict__ hd,
    const float* __restrict__ b1, const float* __restrict__ b2,
    const unsigned short* __restrict__ w2b, float* __restrict__ out)
{
    __shared__ uint4 ldsq[4096];           // 64 KB hid tile
    __shared__ float red[2][64][8];
    char* lds = (char*)ldsq;

    const int bid = blockIdx.x, tid = threadIdx.x;
    const int bm = bid >> 1;               // (b*256+m)
    const int b = bm >> 8;
    const int n0 = (bid & 1) << 6;
    const float* heR = he + bm * 512;
    const float* hdR = hd + (b * 128 + n0) * 512;

    // ---- stage hid = tanh(he + hd + b1) as bf16 into swizzled LDS ----
    const int row = tid >> 3, a = tid & 7;
    #pragma unroll
    for (int i = 0; i < 8; i++) {
        int k0 = (a + 8 * i) * 8;
        const float4* hp = (const float4*)(hdR + row * 512 + k0);
        const float4* ep = (const float4*)(heR + k0);
        const float4* bp = (const float4*)(b1 + k0);
        float4 h0 = hp[0], h1 = hp[1];
        float4 e0 = ep[0], e1 = ep[1];
        float4 v0 = bp[0], v1 = bp[1];
        float4 x0, x1;
        x0.x = tanh_fast(h0.x + e0.x + v0.x);
        x0.y = tanh_fast(h0.y + e0.y + v0.y);
        x0.z = tanh_fast(h0.z + e0.z + v0.z);
        x0.w = tanh_fast(h0.w + e0.w + v0.w);
        x1.x = tanh_fast(h1.x + e1.x + v1.x);
        x1.y = tanh_fast(h1.y + e1.y + v1.y);
        x1.z = tanh_fast(h1.z + e1.z + v1.z);
        x1.w = tanh_fast(h1.w + e1.w + v1.w);
        *(bf16x8*)(lds + swz(row, k0 * 2)) = cvt8(x0, x1);
    }
    __syncthreads();

    // ---- GEMM: no barriers in K-loop; B register double-buffered from L2 ----
    const int lane = tid & 63, wid = tid >> 6, lr = lane & 15, lg = lane >> 4;
    const unsigned short* wb = w2b + (wid * 128 + lr) * 512 + lg * 8;

    f32x4 acc[4][8];
    #pragma unroll
    for (int rt = 0; rt < 4; rt++)
        #pragma unroll
        for (int ct = 0; ct < 8; ct++)
            acc[rt][ct] = f32x4{0.f, 0.f, 0.f, 0.f};

    bf16x8 bA[8], bB[8];
    #pragma unroll
    for (int ct = 0; ct < 8; ct++)
        bA[ct] = *(const bf16x8*)(wb + ct * 8192);

    #pragma unroll 1
    for (int kk = 0; kk < 512; kk += 64) {
        // prefetch next 32-k B slice while doing MFMAs on bA
        #pragma unroll
        for (int ct = 0; ct < 8; ct++)
            bB[ct] = *(const bf16x8*)(wb + ct * 8192 + kk + 32);
        {
            bf16x8 af[4];
            #pragma unroll
            for (int rt = 0; rt < 4; rt++)
                af[rt] = *(const bf16x8*)(lds + swz(rt * 16 + lr, kk * 2 + lg * 16));
            #pragma unroll
            for (int ct = 0; ct < 8; ct++)
                #pragma unroll
                for (int rt = 0; rt < 4; rt++)
                    acc[rt][ct] = __builtin_amdgcn_mfma_f32_16x16x32_bf16(af[rt], bA[ct], acc[rt][ct], 0, 0, 0);
        }
        {
            int kn = (kk + 64) & 511;   // last iter wraps to 0: redundant, harmless
            #pragma unroll
            for (int ct = 0; ct < 8; ct++)
                bA[ct] = *(const bf16x8*)(wb + ct * 8192 + kn);
        }
        {
            bf16x8 af[4];
            #pragma unroll
            for (int rt = 0; rt < 4; rt++)
                af[rt] = *(const bf16x8*)(lds + swz(rt * 16 + lr, (kk + 32) * 2 + lg * 16));
            #pragma unroll
            for (int ct = 0; ct < 8; ct++)
                #pragma unroll
                for (int rt = 0; rt < 4; rt++)
                    acc[rt][ct] = __builtin_amdgcn_mfma_f32_16x16x32_bf16(af[rt], bB[ct], acc[rt][ct], 0, 0, 0);
        }
    }

    // ---- epilogue: +b2, then log_softmax over the 1024 columns of each row ----
    float b2v[8];
    #pragma unroll
    for (int ct = 0; ct < 8; ct++) b2v[ct] = b2[wid * 128 + ct * 16 + lr];
    #pragma unroll
    for (int rt = 0; rt < 4; rt++)
        #pragma unroll
        for (int ct = 0; ct < 8; ct++)
            #pragma unroll
            for (int reg = 0; reg < 4; reg++)
                acc[rt][ct][reg] += b2v[ct];

    // C/D layout: col = lane&15, row = (lane>>4)*4 + reg.
    // Row r = rt*16 + lg*4 + reg; the 16 lanes sharing lg hold 16 different cols of r.
    #pragma unroll
    for (int rt = 0; rt < 4; rt++)
        #pragma unroll
        for (int reg = 0; reg < 4; reg++) {
            float m = acc[rt][0][reg];
            #pragma unroll
            for (int ct = 1; ct < 8; ct++) m = fmaxf(m, acc[rt][ct][reg]);
            m = fmaxf(m, __shfl_xor(m, 1));
            m = fmaxf(m, __shfl_xor(m, 2));
            m = fmaxf(m, __shfl_xor(m, 4));
            m = fmaxf(m, __shfl_xor(m, 8));
            if (lr == 0) red[0][rt * 16 + lg * 4 + reg][wid] = m;
        }
    __syncthreads();

    float mx[4][4], logZ[4][4];
    #pragma unroll
    for (int rt = 0; rt < 4; rt++)
        #pragma unroll
        for (int reg = 0; reg < 4; reg++) {
            int r = rt * 16 + lg * 4 + reg;
            float m = red[0][r][0];
            #pragma unroll
            for (int w = 1; w < 8; w++) m = fmaxf(m, red[0][r][w]);
            mx[rt][reg] = m;
            float s = 0.f;
            #pragma unroll
            for (int ct = 0; ct < 8; ct++) s += __expf(acc[rt][ct][reg] - m);
            s += __shfl_xor(s, 1);
            s += __shfl_xor(s, 2);
            s += __shfl_xor(s, 4);
            s += __shfl_xor(s, 8);
            if (lr == 0) red[1][r][wid] = s;
        }
    __syncthreads();

    #pragma unroll
    for (int rt = 0; rt < 4; rt++)
        #pragma unroll
        for (int reg = 0; reg < 4; reg++) {
            int r = rt * 16 + lg * 4 + reg;
            float s = red[1][r][0];
            #pragma unroll
            for (int w = 1; w < 8; w++) s += red[1][r][w];
            logZ[rt][reg] = mx[rt][reg] + __logf(s);
        }

    const size_t ro = (size_t)bid * 64;
    #pragma unroll
    for (int rt = 0; rt < 4; rt++)
        #pragma unroll
        for (int reg = 0; reg < 4; reg++)
            #pragma unroll
            for (int ct = 0; ct < 8; ct++) {   // ct innermost: adjacent 64B chunks combine
                int r = rt * 16 + lg * 4 + reg;
                out[(ro + r) * 1024 + wid * 128 + ct * 16 + lr] = acc[rt][ct][reg] - logZ[rt][reg];
            }
}

extern "C" void kernel_launch(void* const* d_in, const int* in_sizes, int n_in,
                              void* d_out, int out_size, void* d_ws, size_t ws_size,
                              hipStream_t stream) {
    const float* enc = (const float*)d_in[0];
    const float* dec = (const float*)d_in[1];
    const float* w1  = (const float*)d_in[2];
    const float* b1  = (const float*)d_in[3];
    const float* w2  = (const float*)d_in[4];
    const float* b2  = (const float*)d_in[5];

    float* he = (float*)d_ws;                            // 1024*512 f32
    float* hd = he + 1024 * 512;                         // 512*512 f32
    unsigned short* w2b = (unsigned short*)(hd + 512 * 512); // 1024*512 bf16

    k_prep<<<40, 512, 0, stream>>>(enc, dec, w1, w2, he, hd, w2b);
    k_main<<<2048, 512, 0, stream>>>(he, hd, b1, b2, w2b, (float*)d_out);
}

// Round 2
// 479.301 us; speedup vs baseline: 1.0414x; 1.0414x over previous
//
#include <hip/hip_runtime.h>

// RNN-T joint: log_softmax(fc2(tanh(fc1(cat(enc,dec))))), fused.
// B=4, M=256, N=128, D=512, C=1024, JOINT=1024.
// ws layout: he f32 [1024][512] | hd f32 [512][512] | w2b bf16 [1024][512]  (4 MB)

typedef __attribute__((ext_vector_type(8))) __bf16 bf16x8;
typedef __attribute__((ext_vector_type(4))) float f32x4;

__device__ __forceinline__ float tanh_fast(float x) {
    // tanh(x) = 1 - 2/(1+e^{2x}); stable at both extremes (exp->0 or inf)
    float e = __expf(2.0f * x);
    return 1.0f - 2.0f / (e + 1.0f);
}

// Swizzled LDS byte offset for a [64 rows][512 k] bf16 tile (row stride 1024 B).
// XOR of byte bits 4-6 with row&7: stride-1024 ds_read_b128 would otherwise be
// a 16-way bank conflict; with the XOR it is 2-way (free, m136).
__device__ __forceinline__ int swz(int row, int kbyte) {
    return row * 1024 + (kbyte ^ ((row & 7) << 4));
}

__device__ __forceinline__ bf16x8 cvt8(float4 a, float4 b) {
    bf16x8 r;
    r[0] = (__bf16)a.x; r[1] = (__bf16)a.y; r[2] = (__bf16)a.z; r[3] = (__bf16)a.w;
    r[4] = (__bf16)b.x; r[5] = (__bf16)b.y; r[6] = (__bf16)b.z; r[7] = (__bf16)b.w;
    return r;
}

// ---------------------------------------------------------------------------
// Prep: blocks 0..15 -> he (enc @ w1[:, :512]^T), 16..23 -> hd (dec @ w1[:, 512:]^T),
//       blocks 24..39 -> w2 f32 -> bf16 conversion.  (validated in R1)
// ---------------------------------------------------------------------------
__global__ __launch_bounds__(512) void k_prep(
    const float* __restrict__ enc, const float* __restrict__ dec,
    const float* __restrict__ w1, const float* __restrict__ w2,
    float* __restrict__ he, float* __restrict__ hd,
    unsigned short* __restrict__ w2b)
{
    const int bid = blockIdx.x, tid = threadIdx.x;

    if (bid >= 24) {  // w2 conversion: 1024*512 floats = 131072 float4s
        int t = (bid - 24) * 512 + tid;
        const float4* src = (const float4*)w2;
        ushort4* dst = (ushort4*)w2b;
        for (int i = t; i < 131072; i += 8192) {
            float4 v = src[i];
            ushort4 o;
            o.x = __builtin_bit_cast(unsigned short, (__bf16)v.x);
            o.y = __builtin_bit_cast(unsigned short, (__bf16)v.y);
            o.z = __builtin_bit_cast(unsigned short, (__bf16)v.z);
            o.w = __builtin_bit_cast(unsigned short, (__bf16)v.w);
            dst[i] = o;
        }
        return;
    }

    __shared__ uint4 ldsq[4096];           // 64 KB: A tile, 64 rows x 512 k bf16
    char* lds = (char*)ldsq;

    const bool ish = bid < 16;
    const int r0 = (ish ? bid : bid - 16) * 64;
    const float* src = (ish ? enc : dec) + r0 * 512;
    const float* wsrc = w1 + (ish ? 0 : 512);
    float* dst = (ish ? he : hd) + r0 * 512;

    // stage A tile (f32 -> bf16): one wave writes one full row per pass -> conflict-free
    const int lane = tid & 63, wid = tid >> 6;
    #pragma unroll
    for (int j = 0; j < 8; j++) {
        int row = wid * 8 + j;
        const float4* p = (const float4*)(src + row * 512 + lane * 8);
        *(bf16x8*)(lds + swz(row, lane * 16)) = cvt8(p[0], p[1]);
    }
    __syncthreads();

    const int lr = lane & 15, lg = lane >> 4;
    f32x4 acc[4][4];
    #pragma unroll
    for (int rt = 0; rt < 4; rt++)
        #pragma unroll
        for (int ct = 0; ct < 4; ct++)
            acc[rt][ct] = f32x4{0.f, 0.f, 0.f, 0.f};

    #pragma unroll 1
    for (int ks = 0; ks < 512; ks += 32) {
        bf16x8 af[4];
        #pragma unroll
        for (int rt = 0; rt < 4; rt++)
            af[rt] = *(const bf16x8*)(lds + swz(rt * 16 + lr, ks * 2 + lg * 16));
        #pragma unroll
        for (int ct = 0; ct < 4; ct++) {
            int col = wid * 64 + ct * 16 + lr;
            const float4* wp = (const float4*)(wsrc + col * 1024 + ks + lg * 8);
            bf16x8 bfr = cvt8(wp[0], wp[1]);
            #pragma unroll
            for (int rt = 0; rt < 4; rt++)
                acc[rt][ct] = __builtin_amdgcn_mfma_f32_16x16x32_bf16(af[rt], bfr, acc[rt][ct], 0, 0, 0);
        }
    }

    #pragma unroll
    for (int rt = 0; rt < 4; rt++)
        #pragma unroll
        for (int ct = 0; ct < 4; ct++)
            #pragma unroll
            for (int reg = 0; reg < 4; reg++)
                dst[(rt * 16 + lg * 4 + reg) * 512 + wid * 64 + ct * 16 + lr] = acc[rt][ct][reg];
}

// ---------------------------------------------------------------------------
// Main fused kernel: block = 64 output rows (one (b,m), 64 consecutive n) x 1024 cols.
// 1024 threads = 16 waves; wave w owns cols [w*64, w*64+64) -> acc[4][4] = 64 regs/lane.
// __launch_bounds__(1024,4) forces <=128 regs -> 16 waves/CU (2x R1 occupancy).
// ---------------------------------------------------------------------------
__global__ __launch_bounds__(1024, 4) void k_main(
    const float* __restrict__ he, const float* __restrict__ hd,
    const float* __restrict__ b1, const float* __restrict__ b2,
    const unsigned short* __restrict__ w2b, float* __restrict__ out)
{
    __shared__ uint4 ldsq[4096];           // 64 KB hid tile: 64 rows x 512 k bf16
    __shared__ float red[2][64][16];       // cross-wave softmax partials (8 KB)
    char* lds = (char*)ldsq;

    const int bid = blockIdx.x, tid = threadIdx.x;
    const int bm = bid >> 1;               // (b*256+m)
    const int b = bm >> 8;
    const int n0 = (bid & 1) << 6;
    const float* heR = he + bm * 512;
    const float* hdR = hd + (b * 128 + n0) * 512;

    const int lane = tid & 63, w = tid >> 6, lr = lane & 15, lg = lane >> 4;

    // ---- stage hid = tanh(he + hd + b1) as bf16 into swizzled LDS ----
    // wave w stages rows 4w..4w+3; one wave writes one full 1KB row per pass
    // (lane l covers bytes l*16 ^ const -> conflict-free ds_write_b128).
    {
        const float4* ep = (const float4*)(heR + lane * 8);
        const float4* bp = (const float4*)(b1 + lane * 8);
        float4 e0 = ep[0], e1 = ep[1];
        float4 v0 = bp[0], v1 = bp[1];
        #pragma unroll
        for (int j = 0; j < 4; j++) {
            int r = w * 4 + j;
            const float4* hp = (const float4*)(hdR + r * 512 + lane * 8);
            float4 h0 = hp[0], h1 = hp[1];
            float4 x0, x1;
            x0.x = tanh_fast(h0.x + e0.x + v0.x);
            x0.y = tanh_fast(h0.y + e0.y + v0.y);
            x0.z = tanh_fast(h0.z + e0.z + v0.z);
            x0.w = tanh_fast(h0.w + e0.w + v0.w);
            x1.x = tanh_fast(h1.x + e1.x + v1.x);
            x1.y = tanh_fast(h1.y + e1.y + v1.y);
            x1.z = tanh_fast(h1.z + e1.z + v1.z);
            x1.w = tanh_fast(h1.w + e1.w + v1.w);
            *(bf16x8*)(lds + swz(r, lane * 16)) = cvt8(x0, x1);
        }
    }
    __syncthreads();

    // ---- GEMM: no barriers in K-loop; B register double-buffered from L2 ----
    const unsigned short* wb = w2b + (w * 64 + lr) * 512 + lg * 8;

    f32x4 acc[4][4];
    #pragma unroll
    for (int rt = 0; rt < 4; rt++)
        #pragma unroll
        for (int ct = 0; ct < 4; ct++)
            acc[rt][ct] = f32x4{0.f, 0.f, 0.f, 0.f};

    bf16x8 bA[4], bB[4];
    #pragma unroll
    for (int ct = 0; ct < 4; ct++)
        bA[ct] = *(const bf16x8*)(wb + ct * 8192);

    #pragma unroll 1
    for (int kk = 0; kk < 512; kk += 64) {
        #pragma unroll
        for (int ct = 0; ct < 4; ct++)
            bB[ct] = *(const bf16x8*)(wb + ct * 8192 + kk + 32);
        {
            bf16x8 af[4];
            #pragma unroll
            for (int rt = 0; rt < 4; rt++)
                af[rt] = *(const bf16x8*)(lds + swz(rt * 16 + lr, kk * 2 + lg * 16));
            __builtin_amdgcn_s_setprio(1);
            #pragma unroll
            for (int ct = 0; ct < 4; ct++)
                #pragma unroll
                for (int rt = 0; rt < 4; rt++)
                    acc[rt][ct] = __builtin_amdgcn_mfma_f32_16x16x32_bf16(af[rt], bA[ct], acc[rt][ct], 0, 0, 0);
            __builtin_amdgcn_s_setprio(0);
        }
        {
            int kn = (kk + 64) & 511;   // last iter wraps to 0: redundant, harmless
            #pragma unroll
            for (int ct = 0; ct < 4; ct++)
                bA[ct] = *(const bf16x8*)(wb + ct * 8192 + kn);
        }
        {
            bf16x8 af[4];
            #pragma unroll
            for (int rt = 0; rt < 4; rt++)
                af[rt] = *(const bf16x8*)(lds + swz(rt * 16 + lr, (kk + 32) * 2 + lg * 16));
            __builtin_amdgcn_s_setprio(1);
            #pragma unroll
            for (int ct = 0; ct < 4; ct++)
                #pragma unroll
                for (int rt = 0; rt < 4; rt++)
                    acc[rt][ct] = __builtin_amdgcn_mfma_f32_16x16x32_bf16(af[rt], bB[ct], acc[rt][ct], 0, 0, 0);
            __builtin_amdgcn_s_setprio(0);
        }
    }

    // ---- epilogue: +b2, then log_softmax over the 1024 columns of each row ----
    {
        float b2v[4];
        #pragma unroll
        for (int ct = 0; ct < 4; ct++) b2v[ct] = b2[w * 64 + ct * 16 + lr];
        #pragma unroll
        for (int rt = 0; rt < 4; rt++)
            #pragma unroll
            for (int ct = 0; ct < 4; ct++)
                #pragma unroll
                for (int reg = 0; reg < 4; reg++)
                    acc[rt][ct][reg] += b2v[ct];
    }

    // C/D layout: col = lane&15, row = (lane>>4)*4 + reg. Row r = rt*16 + lg*4 + reg.
    // Wave-partial max over this wave's 64 cols -> red[0][r][w].
    #pragma unroll
    for (int rt = 0; rt < 4; rt++)
        #pragma unroll
        for (int reg = 0; reg < 4; reg++) {
            float m = acc[rt][0][reg];
            #pragma unroll
            for (int ct = 1; ct < 4; ct++) m = fmaxf(m, acc[rt][ct][reg]);
            m = fmaxf(m, __shfl_xor(m, 1));
            m = fmaxf(m, __shfl_xor(m, 2));
            m = fmaxf(m, __shfl_xor(m, 4));
            m = fmaxf(m, __shfl_xor(m, 8));
            if (lr == 0) red[0][rt * 16 + lg * 4 + reg][w] = m;
        }
    __syncthreads();

    float mx[4][4];
    #pragma unroll
    for (int rt = 0; rt < 4; rt++)
        #pragma unroll
        for (int reg = 0; reg < 4; reg++) {
            int r = rt * 16 + lg * 4 + reg;
            const float4* rp = (const float4*)&red[0][r][0];
            float4 q0 = rp[0], q1 = rp[1], q2 = rp[2], q3 = rp[3];
            float m = fmaxf(fmaxf(fmaxf(q0.x, q0.y), fmaxf(q0.z, q0.w)),
                            fmaxf(fmaxf(q1.x, q1.y), fmaxf(q1.z, q1.w)));
            m = fmaxf(m, fmaxf(fmaxf(fmaxf(q2.x, q2.y), fmaxf(q2.z, q2.w)),
                               fmaxf(fmaxf(q3.x, q3.y), fmaxf(q3.z, q3.w))));
            mx[rt][reg] = m;
            float s = 0.f;
            #pragma unroll
            for (int ct = 0; ct < 4; ct++) s += __expf(acc[rt][ct][reg] - m);
            s += __shfl_xor(s, 1);
            s += __shfl_xor(s, 2);
            s += __shfl_xor(s, 4);
            s += __shfl_xor(s, 8);
            if (lr == 0) red[1][r][w] = s;
        }
    __syncthreads();

    float logZ[4][4];
    #pragma unroll
    for (int rt = 0; rt < 4; rt++)
        #pragma unroll
        for (int reg = 0; reg < 4; reg++) {
            int r = rt * 16 + lg * 4 + reg;
            const float4* rp = (const float4*)&red[1][r][0];
            float4 q0 = rp[0], q1 = rp[1], q2 = rp[2], q3 = rp[3];
            float s = (q0.x + q0.y + q0.z + q0.w) + (q1.x + q1.y + q1.z + q1.w)
                    + (q2.x + q2.y + q2.z + q2.w) + (q3.x + q3.y + q3.z + q3.w);
            logZ[rt][reg] = mx[rt][reg] + __logf(s);
        }

    const size_t ro = (size_t)bid * 64;
    #pragma unroll
    for (int rt = 0; rt < 4; rt++)
        #pragma unroll
        for (int reg = 0; reg < 4; reg++)
            #pragma unroll
            for (int ct = 0; ct < 4; ct++) {
                int r = rt * 16 + lg * 4 + reg;
                out[(ro + r) * 1024 + w * 64 + ct * 16 + lr] = acc[rt][ct][reg] - logZ[rt][reg];
            }
}

extern "C" void kernel_launch(void* const* d_in, const int* in_sizes, int n_in,
                              void* d_out, int out_size, void* d_ws, size_t ws_size,
                              hipStream_t stream) {
    const float* enc = (const float*)d_in[0];
    const float* dec = (const float*)d_in[1];
    const float* w1  = (const float*)d_in[2];
    const float* b1  = (const float*)d_in[3];
    const float* w2  = (const float*)d_in[4];
    const float* b2  = (const float*)d_in[5];

    float* he = (float*)d_ws;                            // 1024*512 f32
    float* hd = he + 1024 * 512;                         // 512*512 f32
    unsigned short* w2b = (unsigned short*)(hd + 512 * 512); // 1024*512 bf16

    k_prep<<<40, 512, 0, stream>>>(enc, dec, w1, w2, he, hd, w2b);
    k_main<<<2048, 1024, 0, stream>>>(he, hd, b1, b2, w2b, (float*)d_out);
}

// Round 3
// 336.563 us; speedup vs baseline: 1.4830x; 1.4241x over previous
//
#include <hip/hip_runtime.h>

// RNN-T joint: log_softmax(fc2(tanh(fc1(cat(enc,dec))))), fused.
// B=4, M=256, N=128, D=512, C=1024, JOINT=1024.
// ws: heb f32 [1024][512] (he+b1) | hdb bf16 [512][512] | w2p bf16 frag-packed [64*16*64*8]
//
// R3 theory: R2 was serialized on (a) 16-segment scattered B-loads, (b) 8-way
// LDS conflicts from a broken XOR swizzle. Fix: fragment-linear layouts so
// every hot load/store is lane-contiguous (1KB per wave inst).

typedef __attribute__((ext_vector_type(8))) __bf16 bf16x8;
typedef __attribute__((ext_vector_type(8))) unsigned short u16x8;
typedef __attribute__((ext_vector_type(4))) float f32x4;

__device__ __forceinline__ float tanh_fast(float x) {
    // tanh(x) = 1 - 2/(1+e^{2x}); stable at both extremes
    float e = __expf(2.0f * x);
    return 1.0f - 2.0f / (e + 1.0f);
}
__device__ __forceinline__ float bf2f(unsigned short u) {
    return __builtin_bit_cast(float, (unsigned)u << 16);
}
__device__ __forceinline__ unsigned short f2bf(float f) {
    return __builtin_bit_cast(unsigned short, (__bf16)f);
}

// k_prep-only LDS swizzle (legacy layout, small kernel, not worth reworking)
__device__ __forceinline__ int swz(int row, int kbyte) {
    return row * 1024 + (kbyte ^ ((row & 7) << 4));
}

__device__ __forceinline__ bf16x8 cvt8(float4 a, float4 b) {
    bf16x8 r;
    r[0] = (__bf16)a.x; r[1] = (__bf16)a.y; r[2] = (__bf16)a.z; r[3] = (__bf16)a.w;
    r[4] = (__bf16)b.x; r[5] = (__bf16)b.y; r[6] = (__bf16)b.z; r[7] = (__bf16)b.w;
    return r;
}

// ---------------------------------------------------------------------------
// Prep: blocks 0..15 -> heb = enc @ w1enc^T + b1 (f32),
//       blocks 16..23 -> hdb = bf16(dec @ w1dec^T) row-major,
//       blocks 24..39 -> w2 f32 -> w2p bf16 in MFMA B-fragment order:
//         chunk((c>>4)*16 + k>>5)*64 + ((k>>3)&3)*16 + (c&15), 8 shorts each.
// ---------------------------------------------------------------------------
__global__ __launch_bounds__(512) void k_prep(
    const float* __restrict__ enc, const float* __restrict__ dec,
    const float* __restrict__ w1, const float* __restrict__ b1,
    const float* __restrict__ w2,
    float* __restrict__ heb, unsigned short* __restrict__ hdb,
    unsigned short* __restrict__ w2p)
{
    const int bid = blockIdx.x, tid = threadIdx.x;

    if (bid >= 24) {  // pack w2 -> w2p
        int t = (bid - 24) * 512 + tid;          // 0..8191
        #pragma unroll
        for (int i = 0; i < 8; ++i) {
            int p = t + i * 8192;                // 0..65535 = (c, kchunk8)
            int c = p >> 6, kc = p & 63;
            const float4* s = (const float4*)(w2 + c * 512 + kc * 8);
            float4 a = s[0], bq = s[1];
            u16x8 o;
            o[0] = f2bf(a.x);  o[1] = f2bf(a.y);  o[2] = f2bf(a.z);  o[3] = f2bf(a.w);
            o[4] = f2bf(bq.x); o[5] = f2bf(bq.y); o[6] = f2bf(bq.z); o[7] = f2bf(bq.w);
            int kt = kc >> 2, lg = kc & 3;
            int chunk = ((c >> 4) * 16 + kt) * 64 + lg * 16 + (c & 15);
            *(u16x8*)(w2p + chunk * 8) = o;
        }
        return;
    }

    __shared__ uint4 ldsq[4096];           // 64 KB A tile
    char* lds = (char*)ldsq;

    const bool ish = bid < 24 && bid >= 16 ? false : true;
    const int r0 = (bid < 16 ? bid : bid - 16) * 64;
    const float* src = (bid < 16 ? enc : dec) + r0 * 512;
    const float* wsrc = w1 + (bid < 16 ? 0 : 512);

    // stage A tile (f32 -> bf16): one wave writes one full row per pass
    const int lane = tid & 63, wid = tid >> 6;
    #pragma unroll
    for (int j = 0; j < 8; j++) {
        int row = wid * 8 + j;
        const float4* p = (const float4*)(src + row * 512 + lane * 8);
        *(bf16x8*)(lds + swz(row, lane * 16)) = cvt8(p[0], p[1]);
    }
    __syncthreads();

    const int lr = lane & 15, lg = lane >> 4;
    f32x4 acc[4][4];
    #pragma unroll
    for (int rt = 0; rt < 4; rt++)
        #pragma unroll
        for (int ct = 0; ct < 4; ct++)
            acc[rt][ct] = f32x4{0.f, 0.f, 0.f, 0.f};

    #pragma unroll 1
    for (int ks = 0; ks < 512; ks += 32) {
        bf16x8 af[4];
        #pragma unroll
        for (int rt = 0; rt < 4; rt++)
            af[rt] = *(const bf16x8*)(lds + swz(rt * 16 + lr, ks * 2 + lg * 16));
        #pragma unroll
        for (int ct = 0; ct < 4; ct++) {
            int col = wid * 64 + ct * 16 + lr;
            const float4* wp = (const float4*)(wsrc + col * 1024 + ks + lg * 8);
            bf16x8 bfr = cvt8(wp[0], wp[1]);
            #pragma unroll
            for (int rt = 0; rt < 4; rt++)
                acc[rt][ct] = __builtin_amdgcn_mfma_f32_16x16x32_bf16(af[rt], bfr, acc[rt][ct], 0, 0, 0);
        }
    }

    if (bid < 16) {  // heb = he + b1
        float b1v[4];
        #pragma unroll
        for (int ct = 0; ct < 4; ct++) b1v[ct] = b1[wid * 64 + ct * 16 + lr];
        #pragma unroll
        for (int rt = 0; rt < 4; rt++)
            #pragma unroll
            for (int ct = 0; ct < 4; ct++)
                #pragma unroll
                for (int reg = 0; reg < 4; reg++)
                    heb[(r0 + rt * 16 + lg * 4 + reg) * 512 + wid * 64 + ct * 16 + lr] =
                        acc[rt][ct][reg] + b1v[ct];
    } else {         // hdb bf16 row-major
        #pragma unroll
        for (int rt = 0; rt < 4; rt++)
            #pragma unroll
            for (int ct = 0; ct < 4; ct++)
                #pragma unroll
                for (int reg = 0; reg < 4; reg++)
                    hdb[(r0 + rt * 16 + lg * 4 + reg) * 512 + wid * 64 + ct * 16 + lr] =
                        f2bf(acc[rt][ct][reg]);
    }
    (void)ish;
}

// ---------------------------------------------------------------------------
// Main fused kernel: block = 64 rows (one (b,m), 64 n's) x 1024 cols, 16 waves.
// hid tile stored in LDS in A-fragment-linear order:
//   region (rt,kt) at byte ((rt*16+kt)*64 + lane)*16, lane's chunk =
//   row rt*16+(lane&15), k = kt*32+(lane>>4)*8 .. +7  (contiguous 1KB/region).
// All K-loop LDS reads + B loads are lane-contiguous -> conflict/segment-free.
// ---------------------------------------------------------------------------
__global__ __launch_bounds__(1024, 4) void k_main(
    const float* __restrict__ heb, const unsigned short* __restrict__ hdb,
    const float* __restrict__ b2, const unsigned short* __restrict__ w2p,
    float* __restrict__ out)
{
    __shared__ uint4 ldsq[4096];           // 64 KB hid fragment buffer
    __shared__ float red[2][64][16];       // cross-wave softmax partials
    char* lds = (char*)ldsq;

    const int bid = blockIdx.x, tid = threadIdx.x;
    const int bm = bid >> 1;               // (b*256+m)
    const int b = bm >> 8;
    const int n0 = (bid & 1) << 6;
    const int lane = tid & 63, w = tid >> 6, lr = lane & 15, lg = lane >> 4;

    const float* hebR = heb + bm * 512;

    // ---- stage hid = tanh(heb + hd) bf16, fragment-linear ----
    // wave w: rt = w>>2, kt = (w&3)*4 + it; lane chunk = (row lr, kslice lg)
    {
        const int rt = w >> 2, kt0 = (w & 3) * 4;
        const unsigned short* hb = hdb + (size_t)(b * 128 + n0 + rt * 16 + lr) * 512 + lg * 8;
        const float* ep = hebR + lg * 8;
        char* ld = lds + ((rt * 16) * 64 + lane) * 16;
        #pragma unroll
        for (int it = 0; it < 4; ++it) {
            int kt = kt0 + it;
            u16x8 hv = *(const u16x8*)(hb + kt * 32);
            float4 e0 = *(const float4*)(ep + kt * 32);
            float4 e1 = *(const float4*)(ep + kt * 32 + 4);
            bf16x8 xo;
            xo[0] = (__bf16)tanh_fast(bf2f(hv[0]) + e0.x);
            xo[1] = (__bf16)tanh_fast(bf2f(hv[1]) + e0.y);
            xo[2] = (__bf16)tanh_fast(bf2f(hv[2]) + e0.z);
            xo[3] = (__bf16)tanh_fast(bf2f(hv[3]) + e0.w);
            xo[4] = (__bf16)tanh_fast(bf2f(hv[4]) + e1.x);
            xo[5] = (__bf16)tanh_fast(bf2f(hv[5]) + e1.y);
            xo[6] = (__bf16)tanh_fast(bf2f(hv[6]) + e1.z);
            xo[7] = (__bf16)tanh_fast(bf2f(hv[7]) + e1.w);
            *(bf16x8*)(ld + kt * 1024) = xo;
        }
    }
    __syncthreads();

    // ---- GEMM: barrier-free K-loop, reg-double-buffered B ----
    // B chunk for (ctile=w*4+ct, kt): w2p byte ((ctile*16+kt)*64 + lane)*16
    const char* pw = (const char*)w2p + (w << 16) + (lane << 4);
    const char* la = lds + (lane << 4);

    f32x4 acc[4][4];
    #pragma unroll
    for (int rt = 0; rt < 4; rt++)
        #pragma unroll
        for (int ct = 0; ct < 4; ct++)
            acc[rt][ct] = f32x4{0.f, 0.f, 0.f, 0.f};

    bf16x8 bA[4], bB[4];
    #pragma unroll
    for (int ct = 0; ct < 4; ct++)
        bA[ct] = *(const bf16x8*)(pw + ct * 16384);

    #pragma unroll 1
    for (int kt = 0; kt < 16; kt += 2) {
        #pragma unroll
        for (int ct = 0; ct < 4; ct++)
            bB[ct] = *(const bf16x8*)(pw + ct * 16384 + (kt + 1) * 1024);
        {
            bf16x8 af[4];
            #pragma unroll
            for (int rt = 0; rt < 4; rt++)
                af[rt] = *(const bf16x8*)(la + (rt * 16 + kt) * 1024);
            __builtin_amdgcn_s_setprio(1);
            #pragma unroll
            for (int ct = 0; ct < 4; ct++)
                #pragma unroll
                for (int rt = 0; rt < 4; rt++)
                    acc[rt][ct] = __builtin_amdgcn_mfma_f32_16x16x32_bf16(af[rt], bA[ct], acc[rt][ct], 0, 0, 0);
            __builtin_amdgcn_s_setprio(0);
        }
        #pragma unroll
        for (int ct = 0; ct < 4; ct++)
            bA[ct] = *(const bf16x8*)(pw + ct * 16384 + ((kt + 2) & 15) * 1024);
        {
            bf16x8 af[4];
            #pragma unroll
            for (int rt = 0; rt < 4; rt++)
                af[rt] = *(const bf16x8*)(la + (rt * 16 + kt + 1) * 1024);
            __builtin_amdgcn_s_setprio(1);
            #pragma unroll
            for (int ct = 0; ct < 4; ct++)
                #pragma unroll
                for (int rt = 0; rt < 4; rt++)
                    acc[rt][ct] = __builtin_amdgcn_mfma_f32_16x16x32_bf16(af[rt], bB[ct], acc[rt][ct], 0, 0, 0);
            __builtin_amdgcn_s_setprio(0);
        }
    }

    // ---- epilogue: +b2, log_softmax over 1024 cols, store ----
    {
        float b2v[4];
        #pragma unroll
        for (int ct = 0; ct < 4; ct++) b2v[ct] = b2[w * 64 + ct * 16 + lr];
        #pragma unroll
        for (int rt = 0; rt < 4; rt++)
            #pragma unroll
            for (int ct = 0; ct < 4; ct++)
                #pragma unroll
                for (int reg = 0; reg < 4; reg++)
                    acc[rt][ct][reg] += b2v[ct];
    }

    // C/D layout: col = lane&15, row = lg*4 + reg. Row r = rt*16 + lg*4 + reg.
    #pragma unroll
    for (int rt = 0; rt < 4; rt++)
        #pragma unroll
        for (int reg = 0; reg < 4; reg++) {
            float m = acc[rt][0][reg];
            #pragma unroll
            for (int ct = 1; ct < 4; ct++) m = fmaxf(m, acc[rt][ct][reg]);
            m = fmaxf(m, __shfl_xor(m, 1));
            m = fmaxf(m, __shfl_xor(m, 2));
            m = fmaxf(m, __shfl_xor(m, 4));
            m = fmaxf(m, __shfl_xor(m, 8));
            if (lr == 0) red[0][rt * 16 + lg * 4 + reg][w] = m;
        }
    __syncthreads();

    float mx[4][4];
    #pragma unroll
    for (int rt = 0; rt < 4; rt++)
        #pragma unroll
        for (int reg = 0; reg < 4; reg++) {
            int r = rt * 16 + lg * 4 + reg;
            const float4* rp = (const float4*)&red[0][r][0];
            float4 q0 = rp[0], q1 = rp[1], q2 = rp[2], q3 = rp[3];
            float m = fmaxf(fmaxf(fmaxf(q0.x, q0.y), fmaxf(q0.z, q0.w)),
                            fmaxf(fmaxf(q1.x, q1.y), fmaxf(q1.z, q1.w)));
            m = fmaxf(m, fmaxf(fmaxf(fmaxf(q2.x, q2.y), fmaxf(q2.z, q2.w)),
                               fmaxf(fmaxf(q3.x, q3.y), fmaxf(q3.z, q3.w))));
            mx[rt][reg] = m;
            float s = 0.f;
            #pragma unroll
            for (int ct = 0; ct < 4; ct++) s += __expf(acc[rt][ct][reg] - m);
            s += __shfl_xor(s, 1);
            s += __shfl_xor(s, 2);
            s += __shfl_xor(s, 4);
            s += __shfl_xor(s, 8);
            if (lr == 0) red[1][r][w] = s;
        }
    __syncthreads();

    float logZ[4][4];
    #pragma unroll
    for (int rt = 0; rt < 4; rt++)
        #pragma unroll
        for (int reg = 0; reg < 4; reg++) {
            int r = rt * 16 + lg * 4 + reg;
            const float4* rp = (const float4*)&red[1][r][0];
            float4 q0 = rp[0], q1 = rp[1], q2 = rp[2], q3 = rp[3];
            float s = (q0.x + q0.y + q0.z + q0.w) + (q1.x + q1.y + q1.z + q1.w)
                    + (q2.x + q2.y + q2.z + q2.w) + (q3.x + q3.y + q3.z + q3.w);
            logZ[rt][reg] = mx[rt][reg] + __logf(s);
        }

    const size_t ro = (size_t)bid * 64;
    #pragma unroll
    for (int rt = 0; rt < 4; rt++)
        #pragma unroll
        for (int reg = 0; reg < 4; reg++)
            #pragma unroll
            for (int ct = 0; ct < 4; ct++) {
                int r = rt * 16 + lg * 4 + reg;
                out[(ro + r) * 1024 + w * 64 + ct * 16 + lr] = acc[rt][ct][reg] - logZ[rt][reg];
            }
}

extern "C" void kernel_launch(void* const* d_in, const int* in_sizes, int n_in,
                              void* d_out, int out_size, void* d_ws, size_t ws_size,
                              hipStream_t stream) {
    const float* enc = (const float*)d_in[0];
    const float* dec = (const float*)d_in[1];
    const float* w1  = (const float*)d_in[2];
    const float* b1  = (const float*)d_in[3];
    const float* w2  = (const float*)d_in[4];
    const float* b2  = (const float*)d_in[5];

    float* heb = (float*)d_ws;                                   // 2 MB
    unsigned short* hdb = (unsigned short*)(heb + 1024 * 512);   // 0.5 MB
    unsigned short* w2p = hdb + 512 * 512;                       // 1 MB

    k_prep<<<40, 512, 0, stream>>>(enc, dec, w1, b1, w2, heb, hdb, w2p);
    k_main<<<2048, 1024, 0, stream>>>(heb, hdb, b2, w2p, (float*)d_out);
}